// Round 1
// baseline (51.710 us; speedup 1.0000x reference)
//
#include <hip/hip_runtime.h>

// SpikeLoss: loss = 0.5 * sum((outputs - psp(target))^2)
// psp: syn_t = syn_{t-1}*(1-1/tau) + x_t ; psp_t = syn_t / tau   (scan over last axis, T=32)
//
// Parallel-scan formulation: psp_t = (1/tau) * sum_{s<=t} d^{t-s} x_s, d = 1-1/tau.
// Lane owns 4 consecutive t (one float4); 8 lanes per row of T=32. Fully coalesced.

#define NBLOCKS 2048
#define NTHREADS 256

__global__ __launch_bounds__(NTHREADS) void spike_loss_main(
    const float* __restrict__ outputs,
    const float* __restrict__ target,
    const int* __restrict__ tau_p,
    float* __restrict__ partials,
    int total4)
{
    const float tau = (float)tau_p[0];
    const float d  = 1.0f - 1.0f / tau;   // 0.75 for tau=4 (exact)
    const float inv_tau = 1.0f / tau;
    const float d2 = d * d;
    const float d3 = d2 * d;
    const float d4 = d2 * d2;
    const float d8 = d4 * d4;
    const float d16 = d8 * d8;

    const int lane = threadIdx.x & 63;
    const int j = lane & 7;               // position within 8-lane row segment

    const float4* __restrict__ t4 = (const float4*)target;
    const float4* __restrict__ o4 = (const float4*)outputs;

    float acc = 0.0f;
    const int stride = gridDim.x * blockDim.x;
    for (int g = blockIdx.x * blockDim.x + threadIdx.x; g < total4; g += stride) {
        float4 x = t4[g];

        // local inclusive scan over 4 time steps
        float s0 = x.x;
        float s1 = s0 * d + x.y;
        float s2 = s1 * d + x.z;
        float s3 = s2 * d + x.w;

        // weighted Kogge-Stone inclusive scan of segment totals across 8 lanes:
        // S_j = sum_{i<=j} d^{4(j-i)} * Tot_i
        float S = s3;
        float u;
        u = __shfl_up(S, 1, 8); S += (j >= 1) ? d4  * u : 0.0f;
        u = __shfl_up(S, 2, 8); S += (j >= 2) ? d8  * u : 0.0f;
        u = __shfl_up(S, 4, 8); S += (j >= 4) ? d16 * u : 0.0f;

        // carry-in from previous lanes: contribution at local k is d^{k+1} * S_{j-1}
        float cp = __shfl_up(S, 1, 8);
        cp = (j >= 1) ? cp : 0.0f;
        s0 += cp * d;
        s1 += cp * d2;
        s2 += cp * d3;
        s3 += cp * d4;

        float4 o = o4[g];
        float e0 = o.x - s0 * inv_tau;
        float e1 = o.y - s1 * inv_tau;
        float e2 = o.z - s2 * inv_tau;
        float e3 = o.w - s3 * inv_tau;
        acc += e0 * e0 + e1 * e1 + e2 * e2 + e3 * e3;
    }

    // wave reduce (64 lanes)
    #pragma unroll
    for (int o = 32; o > 0; o >>= 1) acc += __shfl_down(acc, o, 64);

    __shared__ float wsum[NTHREADS / 64];
    if (lane == 0) wsum[threadIdx.x >> 6] = acc;
    __syncthreads();
    if (threadIdx.x == 0) {
        float s = 0.0f;
        #pragma unroll
        for (int w = 0; w < NTHREADS / 64; ++w) s += wsum[w];
        partials[blockIdx.x] = s;
    }
}

__global__ __launch_bounds__(NTHREADS) void spike_loss_final(
    const float* __restrict__ partials, float* __restrict__ out, int n)
{
    float acc = 0.0f;
    for (int i = threadIdx.x; i < n; i += NTHREADS) acc += partials[i];
    #pragma unroll
    for (int o = 32; o > 0; o >>= 1) acc += __shfl_down(acc, o, 64);

    __shared__ float wsum[NTHREADS / 64];
    const int lane = threadIdx.x & 63;
    if (lane == 0) wsum[threadIdx.x >> 6] = acc;
    __syncthreads();
    if (threadIdx.x == 0) {
        float s = 0.0f;
        #pragma unroll
        for (int w = 0; w < NTHREADS / 64; ++w) s += wsum[w];
        out[0] = 0.5f * s;
    }
}

extern "C" void kernel_launch(void* const* d_in, const int* in_sizes, int n_in,
                              void* d_out, int out_size, void* d_ws, size_t ws_size,
                              hipStream_t stream) {
    const float* outputs = (const float*)d_in[0];
    const float* target  = (const float*)d_in[1];
    // d_in[2] = n_steps (unused on device; T=32 baked into the 8-lane-per-row layout)
    const int*   tau_p   = (const int*)d_in[3];

    float* partials = (float*)d_ws;   // NBLOCKS floats, fully overwritten each call
    const int total4 = in_sizes[0] / 4;

    spike_loss_main<<<NBLOCKS, NTHREADS, 0, stream>>>(outputs, target, tau_p, partials, total4);
    spike_loss_final<<<1, NTHREADS, 0, stream>>>(partials, (float*)d_out, NBLOCKS);
}

// Round 2
// 49.470 us; speedup vs baseline: 1.0453x; 1.0453x over previous
//
#include <hip/hip_runtime.h>

// SpikeLoss: loss = 0.5 * sum((outputs - psp(target))^2)
// psp: syn_t = syn_{t-1}*(1-1/tau) + x_t ; psp_t = syn_t / tau   (scan over last axis, T=32)
//
// Parallel-scan formulation: psp_t = (1/tau) * sum_{s<=t} d^{t-s} x_s, d = 1-1/tau.
// Lane owns 4 consecutive t (one float4); 8 lanes per row of T=32. Fully coalesced.
// R1: 4x unroll with upfront loads — 8 outstanding float4 loads/thread for MLP
// (R0 had only 2 in flight; VGPR=16, latency-bound despite 5.19 TB/s effective).

#define NBLOCKS 2048
#define NTHREADS 256

__device__ __forceinline__ float process_one(
    float4 x, float4 o, int j,
    float d, float d2, float d3, float d4, float d8, float d16, float inv_tau)
{
    // local inclusive scan over 4 time steps
    float s0 = x.x;
    float s1 = s0 * d + x.y;
    float s2 = s1 * d + x.z;
    float s3 = s2 * d + x.w;

    // weighted Kogge-Stone inclusive scan of segment totals across 8 lanes
    float S = s3;
    float u;
    u = __shfl_up(S, 1, 8); S += (j >= 1) ? d4  * u : 0.0f;
    u = __shfl_up(S, 2, 8); S += (j >= 2) ? d8  * u : 0.0f;
    u = __shfl_up(S, 4, 8); S += (j >= 4) ? d16 * u : 0.0f;

    // carry-in from previous lanes: contribution at local k is d^{k+1} * S_{j-1}
    float cp = __shfl_up(S, 1, 8);
    cp = (j >= 1) ? cp : 0.0f;
    s0 += cp * d;
    s1 += cp * d2;
    s2 += cp * d3;
    s3 += cp * d4;

    float e0 = o.x - s0 * inv_tau;
    float e1 = o.y - s1 * inv_tau;
    float e2 = o.z - s2 * inv_tau;
    float e3 = o.w - s3 * inv_tau;
    return e0 * e0 + e1 * e1 + e2 * e2 + e3 * e3;
}

__global__ __launch_bounds__(NTHREADS) void spike_loss_main(
    const float* __restrict__ outputs,
    const float* __restrict__ target,
    const int* __restrict__ tau_p,
    float* __restrict__ partials,
    int total4)
{
    const float tau = (float)tau_p[0];
    const float d  = 1.0f - 1.0f / tau;   // 0.75 for tau=4 (exact)
    const float inv_tau = 1.0f / tau;
    const float d2 = d * d;
    const float d3 = d2 * d;
    const float d4 = d2 * d2;
    const float d8 = d4 * d4;
    const float d16 = d8 * d8;

    const int lane = threadIdx.x & 63;
    const int j = lane & 7;               // position within 8-lane row segment

    const float4* __restrict__ t4 = (const float4*)target;
    const float4* __restrict__ o4 = (const float4*)outputs;

    float acc = 0.0f;
    const int stride = gridDim.x * blockDim.x;
    int g = blockIdx.x * blockDim.x + threadIdx.x;

    // main loop: 4 float4-pairs in flight before any dependent math
    for (; g + 3 * stride < total4; g += 4 * stride) {
        float4 x0 = t4[g];
        float4 x1 = t4[g + stride];
        float4 x2 = t4[g + 2 * stride];
        float4 x3 = t4[g + 3 * stride];
        float4 o0 = o4[g];
        float4 o1 = o4[g + stride];
        float4 o2 = o4[g + 2 * stride];
        float4 o3 = o4[g + 3 * stride];

        acc += process_one(x0, o0, j, d, d2, d3, d4, d8, d16, inv_tau);
        acc += process_one(x1, o1, j, d, d2, d3, d4, d8, d16, inv_tau);
        acc += process_one(x2, o2, j, d, d2, d3, d4, d8, d16, inv_tau);
        acc += process_one(x3, o3, j, d, d2, d3, d4, d8, d16, inv_tau);
    }
    // tail (not taken for the bench shape: total4 is an exact multiple of 16*stride/4;
    // 8-lane segments stay convergent because stride is a multiple of 8)
    for (; g < total4; g += stride) {
        acc += process_one(t4[g], o4[g], j, d, d2, d3, d4, d8, d16, inv_tau);
    }

    // wave reduce (64 lanes)
    #pragma unroll
    for (int o = 32; o > 0; o >>= 1) acc += __shfl_down(acc, o, 64);

    __shared__ float wsum[NTHREADS / 64];
    if (lane == 0) wsum[threadIdx.x >> 6] = acc;
    __syncthreads();
    if (threadIdx.x == 0) {
        float s = 0.0f;
        #pragma unroll
        for (int w = 0; w < NTHREADS / 64; ++w) s += wsum[w];
        partials[blockIdx.x] = s;
    }
}

__global__ __launch_bounds__(NTHREADS) void spike_loss_final(
    const float* __restrict__ partials, float* __restrict__ out, int n)
{
    float acc = 0.0f;
    for (int i = threadIdx.x; i < n; i += NTHREADS) acc += partials[i];
    #pragma unroll
    for (int o = 32; o > 0; o >>= 1) acc += __shfl_down(acc, o, 64);

    __shared__ float wsum[NTHREADS / 64];
    const int lane = threadIdx.x & 63;
    if (lane == 0) wsum[threadIdx.x >> 6] = acc;
    __syncthreads();
    if (threadIdx.x == 0) {
        float s = 0.0f;
        #pragma unroll
        for (int w = 0; w < NTHREADS / 64; ++w) s += wsum[w];
        out[0] = 0.5f * s;
    }
}

extern "C" void kernel_launch(void* const* d_in, const int* in_sizes, int n_in,
                              void* d_out, int out_size, void* d_ws, size_t ws_size,
                              hipStream_t stream) {
    const float* outputs = (const float*)d_in[0];
    const float* target  = (const float*)d_in[1];
    // d_in[2] = n_steps (unused on device; T=32 baked into the 8-lane-per-row layout)
    const int*   tau_p   = (const int*)d_in[3];

    float* partials = (float*)d_ws;   // NBLOCKS floats, fully overwritten each call
    const int total4 = in_sizes[0] / 4;

    spike_loss_main<<<NBLOCKS, NTHREADS, 0, stream>>>(outputs, target, tau_p, partials, total4);
    spike_loss_final<<<1, NTHREADS, 0, stream>>>(partials, (float*)d_out, NBLOCKS);
}